// Round 7
// baseline (229.163 us; speedup 1.0000x reference)
//
#include <hip/hip_runtime.h>
#include <hip/hip_bf16.h>

using bf16 = __hip_bfloat16;
typedef __attribute__((ext_vector_type(8))) short short8x;            // 8 bf16 (4 VGPRs)
typedef __attribute__((ext_vector_type(4))) short short4x;            // 4 bf16
typedef __attribute__((ext_vector_type(4))) unsigned short ushort4x;  // 4 bf16 bits
typedef __attribute__((ext_vector_type(4))) float f32x4;              // MFMA accumulator

__device__ __forceinline__ float b2f(bf16 x) { return __bfloat162float(x); }
__device__ __forceinline__ bf16  f2b(float x) { return __float2bfloat16(x); }
__device__ __forceinline__ short bbits(float x) { bf16 b = f2b(x); short s; __builtin_memcpy(&s, &b, 2); return s; }
__device__ __forceinline__ float bu2f(unsigned short s) {
    unsigned v = ((unsigned)s) << 16; float f; __builtin_memcpy(&f, &v, 4); return f;
}
// flag-dispatched input load: f32==1 -> fp32 storage, else bf16 storage
__device__ __forceinline__ float ldin(const void* p, int i, int f32) {
    return f32 ? ((const float*)p)[i] : b2f(((const bf16*)p)[i]);
}

// branchless erf-based gelu (A&S 7.1.26, |eps_erf| <= 1.5e-7)
__device__ __forceinline__ float gelu_f(float x) {
    const float u = x * 0.70710678118654752f;
    const float z = fabsf(u);
    const float t = __builtin_amdgcn_rcpf(fmaf(0.3275911f, z, 1.0f));
    float pl = fmaf(1.061405429f, t, -1.453152027f);
    pl = fmaf(pl, t, 1.421413741f);
    pl = fmaf(pl, t, -0.284496736f);
    pl = fmaf(pl, t, 0.254829592f);
    pl *= t;
    const float e = __builtin_amdgcn_exp2f((z * z) * -1.4426950408889634f);
    float er = fmaf(-pl, e, 1.0f);          // erf(|u|)
    er = __builtin_copysignf(er, u);        // erf(u)
    const float g = 0.5f * x;
    return fmaf(g, er, g);                  // 0.5*x*(1+erf)
}

// problem dims (fixed by setup_inputs)
#define TI 6
#define HI 40
#define WI 40
#define TO 12
#define HO 80
#define WO 80
#define NIN (TI*HI*WI)    // 9600
#define NOUT (TO*HO*WO)   // 76800

// ---------------- workspace layout ----------------
#define F_B1    0                       // [256] effective pw1 bias (o-space)
#define F_ACO   (F_B1 + 256)            // [6][256] rel-coord coefficients (o-space)
#define F_SCW   (F_ACO + 6*256)         // [3][64] (unused, layout kept)
#define F_SCB   (F_SCW + 3*64)          // [3] (unused, layout kept)
#define F_SC    (F_SCB + 4)             // [3][NIN] shortcut conv output
#define F_DT    (F_SC + 3*NIN)          // [2][TO] signed d (t axis)
#define F_DH    (F_DT + 2*TO)           // [2][HO]
#define F_DW    (F_DH + 2*HO)           // [2][WO]
#define F_FT    (F_DW + 2*WO)           // [TO] trilinear frac
#define F_FH    (F_FT + TO)             // [HO]
#define F_FW    (F_FH + HO)             // [WO]
#define F_FC2W  (F_FW + WO)             // [3*256] fc2 weights (fp32 staged)
#define F_FC2B  (F_FC2W + 768)          // [3] fc2 bias (pad 4)
#define F_B2    (F_FC2B + 4)            // [256] fc1-folded bias
#define F_A2    (F_B2 + 256)            // [6][256] fc1-folded coord coeffs
#define F_END   (F_A2 + 6*256)
#define I_IT    0
#define I_IH    (I_IT + 2*TO)
#define I_IW    (I_IH + 2*HO)
#define I_LT0   (I_IW + 2*WO)
#define I_LT1   (I_LT0 + TO)
#define I_LH0   (I_LT1 + TO)
#define I_LH1   (I_LH0 + HO)
#define I_LW0   (I_LH1 + HO)
#define I_LW1   (I_LW0 + WO)
#define I_FLAG  (I_LW1 + WO)
#define I_END   (I_FLAG + 1)

#define MPOS 32     // positions per k_main block
#define ZPAD 264    // bf16 row stride for zt LDS tiles
#define FT_S 72     // bf16 row stride for feat tile (16B-aligned rows)
#define WQS 68      // fp32 row stride for Wq GEMM LDS tiles

// dtype detection (wave-0 ballot over first 64 even halfwords of feat)
__device__ __forceinline__ int detect_f32(const void* feat, int tid, int* sh) {
    if (tid < 64) {
        const unsigned short* u = (const unsigned short*)feat;
        const unsigned e = (u[2 * tid] >> 7) & 0xFFu;
        const unsigned long long m = __ballot(e >= 0x68u && e <= 0x8Eu);
        if (tid == 0) *sh = (__popcll(m) < 32) ? 1 : 0;
    }
    __syncthreads();
    return *sh;
}

// per-axis tables, replicating reference `near` (eps=1e-6, round-half-even) and `lin_idx`
__device__ __forceinline__ void axis_tables(int i, int n_out, int n_in,
                                            float* dvals, int* ivals,
                                            int* l0, int* l1, float* fr) {
    const float r_out = 1.0f / (float)n_out;
    const float r_in  = 1.0f / (float)n_in;
    const float c = -1.0f + r_out + 2.0f * r_out * (float)i;
    #pragma unroll
    for (int v = 0; v < 2; ++v) {
        const float vv = v ? 1.0f : -1.0f;
        float cc = c + vv * r_in + 1e-6f;
        cc = fminf(fmaxf(cc, -1.0f + 1e-6f), 1.0f - 1e-6f);
        float fx = rintf(((cc + 1.0f) * (float)n_in - 1.0f) * 0.5f);
        fx = fminf(fmaxf(fx, 0.0f), (float)(n_in - 1));
        const int idx = (int)fx;
        const float l = -1.0f + r_in + 2.0f * r_in * (float)idx;
        dvals[v * n_out + i] = (c - l) * (float)n_in;
        ivals[v * n_out + i] = idx;
    }
    float x = fminf(fmaxf(((c + 1.0f) * (float)n_in - 1.0f) * 0.5f, 0.0f), (float)(n_in - 1));
    const float x0 = floorf(x);
    fr[i] = x - x0;
    const int i0 = (int)x0;
    l0[i] = i0;
    l1[i] = min(i0 + 1, n_in - 1);
}

// ---------------- kernel W: dedicated Wq-fold GEMM (32 blocks) ----------------
// Wq[j][c'] = (sum_o fc1_w[j][o]*pw1_w[o][24+c']) * dw1_w[24+c'] -> MFMA B-fragments.
// Dedicated kernel so the register allocator can deep-pipeline the LDS reads
// (in the merged k_setup it was capped at 60 VGPRs by the simple fold path -> 44us).
__global__ __launch_bounds__(256, 1)
void k_wq(const void* __restrict__ feat,
          const void* __restrict__ dw1_w, const void* __restrict__ pw1_w,
          const void* __restrict__ fc1_w, bf16* __restrict__ WqP) {
    const int tid = threadIdx.x;
    __shared__ int sflag;
    const int f32 = detect_f32(feat, tid, &sflag);

    __shared__ __align__(16) float fcsT[32 * WQS];   // [32 o][64 j] transposed fc1 chunk
    __shared__ __align__(16) float pws[32 * WQS];    // [32 o][64 ch]
    const int pb = blockIdx.x;               // 0..31
    const int j0 = (pb & 3) * 64;            // j tile base
    const int c0g = (pb >> 2) * 64;          // ch tile base (c' in 0..511)
    const int tj = tid & 15, tc = tid >> 4;  // thread 4x4 register tile
    float acc[4][4] = { {0,0,0,0},{0,0,0,0},{0,0,0,0},{0,0,0,0} };

    for (int oc = 0; oc < 8; ++oc) {
        const int o0 = oc * 32;
        #pragma unroll
        for (int r = 0; r < 8; ++r) {        // fc1_w [64j x 32o] -> fcsT[o][j]
            const int idx = r * 256 + tid;
            const int o = idx & 31, jl = idx >> 5;
            fcsT[o * WQS + jl] = ldin(fc1_w, (j0 + jl) * 256 + o0 + o, f32);
        }
        #pragma unroll
        for (int r = 0; r < 8; ++r) {        // pw1_w [32o x 64ch] -> pws[o][ch]
            const int idx = r * 256 + tid;
            const int ch = idx & 63, o = idx >> 6;
            pws[o * WQS + ch] = ldin(pw1_w, (o0 + o) * 539 + 24 + c0g + ch, f32);
        }
        __syncthreads();
        #pragma unroll
        for (int o = 0; o < 32; ++o) {
            const float4 av = *(const float4*)&fcsT[o * WQS + tj * 4];
            const float4 bv = *(const float4*)&pws[o * WQS + tc * 4];
            const float a4[4] = { av.x, av.y, av.z, av.w };
            const float b4[4] = { bv.x, bv.y, bv.z, bv.w };
            #pragma unroll
            for (int ji = 0; ji < 4; ++ji)
                #pragma unroll
                for (int ci = 0; ci < 4; ++ci)
                    acc[ji][ci] = fmaf(a4[ji], b4[ci], acc[ji][ci]);
        }
        __syncthreads();
    }

    // epilogue: scale by dw1_w, convert, store in MFMA B-fragment layout
    float dsc[4];
    #pragma unroll
    for (int ci = 0; ci < 4; ++ci) dsc[ci] = ldin(dw1_w, 24 + c0g + tc * 4 + ci, f32);
    const int cp0 = c0g + tc * 4;
    const int k2 = cp0 >> 5, e = (cp0 >> 3) & 3, jj0 = cp0 & 7;
    #pragma unroll
    for (int ji = 0; ji < 4; ++ji) {
        const int j = j0 + tj * 4 + ji;
        const int nt = j >> 4, wlo = j & 15;
        const size_t flat = ((((size_t)(k2 * 16 + nt) * 4 + e) * 16 + wlo) * 8 + jj0);
        short v[4];
        #pragma unroll
        for (int ci = 0; ci < 4; ++ci) v[ci] = bbits(acc[ji][ci] * dsc[ci]);
        *(short4x*)&WqP[flat] = *(short4x*)v;
    }
}

// ---------------- kernel A: merged setup (369 blocks) ----------------
// blocks 0..255 : B1/ACO fold per output channel o (block 0 also: tables + small folds)
// blocks 256..368: shortcut conv sc[j][pos] from fp32 feat (self-contained fold)
__global__ __launch_bounds__(256)
void k_setup(const void* __restrict__ feat,
             const void* __restrict__ dw1_w, const void* __restrict__ dw1_b,
             const void* __restrict__ pw1_w, const void* __restrict__ pw1_b,
             const void* __restrict__ fc2_w, const void* __restrict__ fc2_b,
             const void* __restrict__ sc_dw_w, const void* __restrict__ sc_dw_b,
             const void* __restrict__ sc_pw_w, const void* __restrict__ sc_pw_b,
             const void* __restrict__ fc1_b,
             float* __restrict__ F, int* __restrict__ I) {
    const int tid = threadIdx.x;
    const int b = blockIdx.x;
    __shared__ int sflag;
    const int f32 = detect_f32(feat, tid, &sflag);

    if (b >= 256) {           // ---- sc duty: one (j,pos) per thread, fp32 feat ----
        const int g = (b - 256) * 256 + tid;   // 0..28927
        if (g < 3 * NIN) {
            const int j = g / NIN;
            const int pos = g - j * NIN;
            float s = ldin(sc_pw_b, j, f32);
            float a = 0.f;
            for (int c = 0; c < 64; ++c) {
                const float pw = ldin(sc_pw_w, j * 64 + c, f32);
                s += pw * ldin(sc_dw_b, c, f32);
                a = fmaf(pw * ldin(sc_dw_w, c, f32), ldin(feat, c * NIN + pos, f32), a);
            }
            F[F_SC + g] = s + a;
        }
        return;
    }

    // ---- fold duty: B1 + ACO for output channel o = b ----
    __shared__ float row[539];
    __shared__ float red[256];
    const int o = b;

    for (int ch = tid; ch < 539; ch += 256) row[ch] = ldin(pw1_w, o * 539 + ch, f32);
    __syncthreads();

    float s = 0.f;
    for (int ch = tid; ch < 539; ch += 256) s += row[ch] * ldin(dw1_b, ch, f32);
    red[tid] = s;
    __syncthreads();
    for (int st = 128; st > 0; st >>= 1) {
        if (tid < st) red[tid] += red[tid + st];
        __syncthreads();
    }

    if (tid == 0) {
        float bacc = ldin(pw1_b, o, f32) + red[0];
        #pragma unroll
        for (int ch = 536; ch < 539; ++ch)
            bacc += 2.0f * row[ch] * ldin(dw1_w, ch, f32);
        F[F_B1 + o] = bacc;

        float A[6] = {0.f, 0.f, 0.f, 0.f, 0.f, 0.f};
        #pragma unroll
        for (int k = 0; k < 8; ++k) {
            A[(k >> 2)]           += row[3*k + 0] * ldin(dw1_w, 3*k + 0, f32);
            A[2 + ((k >> 1) & 1)] += row[3*k + 1] * ldin(dw1_w, 3*k + 1, f32);
            A[4 + (k & 1)]        += row[3*k + 2] * ldin(dw1_w, 3*k + 2, f32);
        }
        #pragma unroll
        for (int i = 0; i < 6; ++i) F[F_ACO + i * 256 + o] = A[i];
    }

    if (b == 0) {             // ---- prep0 duty ----
        if (tid == 0) I[I_FLAG] = f32;
        for (int r = tid; r < 768; r += 256) F[F_FC2W + r] = ldin(fc2_w, r, f32);
        if (tid < 3) F[F_FC2B + tid] = ldin(fc2_b, tid, f32);
        if (tid < TO) axis_tables(tid, TO, TI, F + F_DT, I + I_IT, I + I_LT0, I + I_LT1, F + F_FT);
        if (tid < HO) axis_tables(tid, HO, HI, F + F_DH, I + I_IH, I + I_LH0, I + I_LH1, F + F_FH);
        if (tid < WO) axis_tables(tid, WO, WI, F + F_DW, I + I_IW, I + I_LW0, I + I_LW1, F + F_FW);
    }
}

// ---------------- kernel B: MFMA corner projections Q + b2/A2 fold ----------------
// grid (301 x 4). pt<300: M=32 positions, corners {2y,2y+1} computed TOGETHER
// (shared A-operand), double-buffered zt, 2 barriers, zero store-drain barriers.
// pt==300,y==0: fold b2/A2 (needs k_setup fold blocks done).
__global__ __launch_bounds__(256)
void k_corner(const void* __restrict__ feat,
              const void* __restrict__ fc1_w, const void* __restrict__ fc1_b,
              float* __restrict__ F, const int* __restrict__ I,
              const bf16* __restrict__ WqP, bf16* __restrict__ Q) {
    const int tid = threadIdx.x;
    const int pt = blockIdx.x, y = blockIdx.y;
    const int f32 = I[I_FLAG];

    if (pt == 300) {          // ---- b2/A2 fold duty ----
        if (y != 0) return;
        const int j = tid;
        float accB = ldin(fc1_b, j, f32);
        float accA[6] = {0.f,0.f,0.f,0.f,0.f,0.f};
        for (int o = 0; o < 256; ++o) {
            const float f = ldin(fc1_w, j * 256 + o, f32);
            accB = fmaf(f, F[F_B1 + o], accB);
            #pragma unroll
            for (int i = 0; i < 6; ++i) accA[i] = fmaf(f, F[F_ACO + i * 256 + o], accA[i]);
        }
        F[F_B2 + j] = accB;
        #pragma unroll
        for (int i = 0; i < 6; ++i) F[F_A2 + i * 256 + j] = accA[i];
        return;
    }

    const int pos0 = pt * 32;
    __shared__ __align__(16) short ft[32 * FT_S];    // feat tile [p][c] bf16
    __shared__ __align__(16) short ztA[32 * ZPAD];   // Q tile corner 2y
    __shared__ __align__(16) short ztB[32 * ZPAD];   // Q tile corner 2y+1

    // stage feat tile (transpose [c][pos] -> [p][c])
    {
        const int p = tid & 31, c0 = tid >> 5;
        #pragma unroll
        for (int cc = 0; cc < 8; ++cc) {
            const int c = c0 * 8 + cc;
            ft[p * FT_S + c] = bbits(ldin(feat, c * NIN + pos0 + p, f32));
        }
    }
    __syncthreads();

    const int wl = tid & 63, w = tid >> 6;
    const int col = wl & 15, quad = wl >> 4;
    const short8x* bp = (const short8x*)WqP;
    const int kA = y * 2, kB = y * 2 + 1;

    f32x4 accA[2][4] = { { {0,0,0,0},{0,0,0,0},{0,0,0,0},{0,0,0,0} },
                         { {0,0,0,0},{0,0,0,0},{0,0,0,0},{0,0,0,0} } };
    f32x4 accB[2][4] = { { {0,0,0,0},{0,0,0,0},{0,0,0,0},{0,0,0,0} },
                         { {0,0,0,0},{0,0,0,0},{0,0,0,0},{0,0,0,0} } };
    #pragma unroll
    for (int kc = 0; kc < 2; ++kc) {
        const short8x a0 = *(const short8x*)&ft[col * FT_S + kc * 32 + quad * 8];
        const short8x a1 = *(const short8x*)&ft[(col + 16) * FT_S + kc * 32 + quad * 8];
        #pragma unroll
        for (int nt = 0; nt < 4; ++nt) {
            const short8x bbA = bp[((kA * 2 + kc) * 16 + (w * 4 + nt)) * 64 + wl];
            const short8x bbB = bp[((kB * 2 + kc) * 16 + (w * 4 + nt)) * 64 + wl];
            accA[0][nt] = __builtin_amdgcn_mfma_f32_16x16x32_bf16(a0, bbA, accA[0][nt], 0, 0, 0);
            accA[1][nt] = __builtin_amdgcn_mfma_f32_16x16x32_bf16(a1, bbA, accA[1][nt], 0, 0, 0);
            accB[0][nt] = __builtin_amdgcn_mfma_f32_16x16x32_bf16(a0, bbB, accB[0][nt], 0, 0, 0);
            accB[1][nt] = __builtin_amdgcn_mfma_f32_16x16x32_bf16(a1, bbB, accB[1][nt], 0, 0, 0);
        }
    }

    // write both accumulators to LDS tiles (D layout: m=quad*4+r, n=w*64+nt*16+col)
    #pragma unroll
    for (int mt = 0; mt < 2; ++mt)
        #pragma unroll
        for (int nt = 0; nt < 4; ++nt) {
            const int n = w * 64 + nt * 16 + col;
            #pragma unroll
            for (int r = 0; r < 4; ++r) {
                const int m = (mt * 16 + quad * 4 + r) * ZPAD + n;
                ztA[m] = bbits(accA[mt][nt][r]);
                ztB[m] = bbits(accB[mt][nt][r]);
            }
        }
    __syncthreads();

    // coalesced stores: 32 rows x 512B per corner; no drain until kernel end
    #pragma unroll
    for (int q = 0; q < 4; ++q) {
        const int i = q * 256 + tid;
        const int p = i >> 5, c8 = i & 31;
        const short8x vA = *(const short8x*)&ztA[p * ZPAD + c8 * 8];
        *(short8x*)(Q + ((size_t)(kA * NIN + pos0 + p)) * 256 + c8 * 8) = vA;
    }
    #pragma unroll
    for (int q = 0; q < 4; ++q) {
        const int i = q * 256 + tid;
        const int p = i >> 5, c8 = i & 31;
        const short8x vB = *(const short8x*)&ztB[p * ZPAD + c8 * 8];
        *(short8x*)(Q + ((size_t)(kB * NIN + pos0 + p)) * 256 + c8 * 8) = vB;
    }
}

// ---------------- kernel C: main fused gather->gelu->fc2 (fc1 pre-folded into Q) ----------------
__global__ __launch_bounds__(256, 4)
void k_main(const bf16* __restrict__ Q, const float* __restrict__ F,
            const int* __restrict__ I, void* __restrict__ outv) {
    const int tid = threadIdx.x;
    const int pos0 = blockIdx.x * MPOS;
    const int f32 = I[I_FLAG];

    __shared__ int   sh_ipos[MPOS][8];
    __shared__ float sh_wk[MPOS][8];
    __shared__ float sh_dv[MPOS][6];
    __shared__ float sh_g[3][MPOS];
    __shared__ float redc[4][4][8][3];   // [wave][16-lane grp][pp][jj]

    const int og = tid & 63, pg = tid >> 6;
    const int j4 = og * 4;
    const float4 b2v = *(const float4*)&F[F_B2 + j4];
    float4 A2v[6];
    #pragma unroll
    for (int i = 0; i < 6; ++i) A2v[i] = *(const float4*)&F[F_A2 + i * 256 + j4];
    const float4 fw0 = *(const float4*)&F[F_FC2W + j4];
    const float4 fw1 = *(const float4*)&F[F_FC2W + 256 + j4];
    const float4 fw2 = *(const float4*)&F[F_FC2W + 512 + j4];

    // ---- stage 1: per-position scalars (threads 0..31) ----
    if (tid < MPOS) {
        const int p = tid;
        const int pos = pos0 + p;
        const int t = pos / (HO * WO);
        const int rem = pos - t * (HO * WO);
        const int h = rem / WO;
        const int w = rem - h * WO;
        const int   iTa[2] = { I[I_IT + t], I[I_IT + TO + t] };
        const float dTv[2] = { F[F_DT + t], F[F_DT + TO + t] };
        const int   iHa[2] = { I[I_IH + h], I[I_IH + HO + h] };
        const float dHv[2] = { F[F_DH + h], F[F_DH + HO + h] };
        const int   iWa[2] = { I[I_IW + w], I[I_IW + WO + w] };
        const float dWv[2] = { F[F_DW + w], F[F_DW + WO + w] };
        sh_dv[p][0] = dTv[0]; sh_dv[p][1] = dTv[1];
        sh_dv[p][2] = dHv[0]; sh_dv[p][3] = dHv[1];
        sh_dv[p][4] = dWv[0]; sh_dv[p][5] = dWv[1];
        const float aT[2] = { fabsf(dTv[0]), fabsf(dTv[1]) };
        const float aH[2] = { fabsf(dHv[0]), fabsf(dHv[1]) };
        const float aW[2] = { fabsf(dWv[0]), fabsf(dWv[1]) };
        const float tot = (aT[0] + aT[1]) * (aH[0] + aH[1]) * (aW[0] + aW[1]) + 8e-9f;
        #pragma unroll
        for (int k = 0; k < 8; ++k) {
            const int at = k >> 2, ah = (k >> 1) & 1, aw = k & 1;
            sh_wk[p][k] = (aT[1 - at] * aH[1 - ah] * aW[1 - aw] + 1e-9f) / tot;
            sh_ipos[p][k] = iTa[at] * (HI * WI) + iHa[ah] * WI + iWa[aw];
        }
        // trilinear shortcut g
        const int a0 = I[I_LT0 + t], a1 = I[I_LT1 + t];
        const int bh0 = I[I_LH0 + h], bh1 = I[I_LH1 + h];
        const int c0 = I[I_LW0 + w], c1 = I[I_LW1 + w];
        const float fT = F[F_FT + t], fH = F[F_FH + h], fW = F[F_FW + w];
        #pragma unroll
        for (int jj = 0; jj < 3; ++jj) {
            const float* Sj = F + F_SC + jj * NIN;
            const int i0 = a0 * (HI * WI), i1 = a1 * (HI * WI);
            const float v000 = Sj[i0 + bh0 * WI + c0], v001 = Sj[i0 + bh0 * WI + c1];
            const float v010 = Sj[i0 + bh1 * WI + c0], v011 = Sj[i0 + bh1 * WI + c1];
            const float v100 = Sj[i1 + bh0 * WI + c0], v101 = Sj[i1 + bh0 * WI + c1];
            const float v110 = Sj[i1 + bh1 * WI + c0], v111 = Sj[i1 + bh1 * WI + c1];
            const float u00 = v000 * (1.f - fT) + v100 * fT;
            const float u01 = v001 * (1.f - fT) + v101 * fT;
            const float u10 = v010 * (1.f - fT) + v110 * fT;
            const float u11 = v011 * (1.f - fT) + v111 * fT;
            const float q0 = u00 * (1.f - fH) + u10 * fH;
            const float q1 = u01 * (1.f - fH) + u11 * fH;
            sh_g[jj][p] = q0 * (1.f - fW) + q1 * fW;
        }
    }
    __syncthreads();

    // ---- stage 2: gather + gelu + fc2 partials ----
    #pragma unroll
    for (int pp = 0; pp < 8; ++pp) {
        const int p = pg * 8 + pp;
        float a0 = b2v.x, a1 = b2v.y, a2 = b2v.z, a3 = b2v.w;
        #pragma unroll
        for (int i = 0; i < 6; ++i) {
            const float dv = sh_dv[p][i];
            a0 = fmaf(A2v[i].x, dv, a0); a1 = fmaf(A2v[i].y, dv, a1);
            a2 = fmaf(A2v[i].z, dv, a2); a3 = fmaf(A2v[i].w, dv, a3);
        }
        #pragma unroll
        for (int k = 0; k < 8; ++k) {
            const float wk = sh_wk[p][k];
            const ushort4x u = *(const ushort4x*)(Q + ((size_t)(k * NIN + sh_ipos[p][k])) * 256 + j4);
            a0 = fmaf(wk, bu2f(u.x), a0); a1 = fmaf(wk, bu2f(u.y), a1);
            a2 = fmaf(wk, bu2f(u.z), a2); a3 = fmaf(wk, bu2f(u.w), a3);
        }
        const float h0 = gelu_f(a0), h1 = gelu_f(a1), h2 = gelu_f(a2), h3 = gelu_f(a3);
        float pj0 = h0 * fw0.x; pj0 = fmaf(h1, fw0.y, pj0); pj0 = fmaf(h2, fw0.z, pj0); pj0 = fmaf(h3, fw0.w, pj0);
        float pj1 = h0 * fw1.x; pj1 = fmaf(h1, fw1.y, pj1); pj1 = fmaf(h2, fw1.z, pj1); pj1 = fmaf(h3, fw1.w, pj1);
        float pj2 = h0 * fw2.x; pj2 = fmaf(h1, fw2.y, pj2); pj2 = fmaf(h2, fw2.z, pj2); pj2 = fmaf(h3, fw2.w, pj2);
        #pragma unroll
        for (int m = 1; m <= 8; m <<= 1) {
            pj0 += __shfl_xor(pj0, m, 64);
            pj1 += __shfl_xor(pj1, m, 64);
            pj2 += __shfl_xor(pj2, m, 64);
        }
        if ((og & 15) == 0) {
            const int grp = og >> 4;
            redc[pg][grp][pp][0] = pj0;
            redc[pg][grp][pp][1] = pj1;
            redc[pg][grp][pp][2] = pj2;
        }
    }
    __syncthreads();

    // ---- stage 3: combine + shortcut + store ----
    if (tid < 96) {
        const int p = tid / 3, jj = tid - 3 * p;
        float a = F[F_FC2B + jj] + sh_g[jj][p];
        #pragma unroll
        for (int g4 = 0; g4 < 4; ++g4) a += redc[p >> 3][g4][p & 7][jj];
        const int oidx = jj * NOUT + pos0 + p;
        if (f32) ((float*)outv)[oidx] = a;
        else     ((bf16*)outv)[oidx] = f2b(a);
    }
}

extern "C" void kernel_launch(void* const* d_in, const int* in_sizes, int n_in,
                              void* d_out, int out_size, void* d_ws, size_t ws_size,
                              hipStream_t stream) {
    const void* feat    = d_in[0];
    const void* dw1_w   = d_in[1];
    const void* dw1_b   = d_in[2];
    const void* pw1_w   = d_in[3];
    const void* pw1_b   = d_in[4];
    const void* fc1_w   = d_in[5];
    const void* fc1_b   = d_in[6];
    const void* fc2_w   = d_in[7];
    const void* fc2_b   = d_in[8];
    const void* sc_dw_w = d_in[9];
    const void* sc_dw_b = d_in[10];
    const void* sc_pw_w = d_in[11];
    const void* sc_pw_b = d_in[12];

    const size_t Q_BYTES   = (size_t)8 * NIN * 256 * 2;   // 39,321,600
    const size_t WQP_BYTES = (size_t)16384 * 8 * 2;       // 262,144
    bf16*  Q    = (bf16*)d_ws;
    bf16*  WqP  = (bf16*)((char*)d_ws + Q_BYTES);
    float* F    = (float*)((char*)d_ws + Q_BYTES + WQP_BYTES);
    int*   I    = (int*)(F + F_END);
    // total ws need ~39.7 MB

    k_wq<<<32, 256, 0, stream>>>(feat, dw1_w, pw1_w, fc1_w, WqP);
    k_setup<<<369, 256, 0, stream>>>(feat, dw1_w, dw1_b, pw1_w, pw1_b,
                                     fc2_w, fc2_b, sc_dw_w, sc_dw_b, sc_pw_w, sc_pw_b,
                                     fc1_b, F, I);
    k_corner<<<dim3(301, 4), 256, 0, stream>>>(feat, fc1_w, fc1_b, F, I, WqP, Q);
    k_main<<<NOUT / MPOS, 256, 0, stream>>>(Q, F, I, (void*)d_out);
}

// Round 10
// 158.884 us; speedup vs baseline: 1.4423x; 1.4423x over previous
//
#include <hip/hip_runtime.h>
#include <hip/hip_bf16.h>

using bf16 = __hip_bfloat16;
typedef __attribute__((ext_vector_type(8))) short short8x;            // 8 bf16 (4 VGPRs)
typedef __attribute__((ext_vector_type(4))) short short4x;            // 4 bf16
typedef __attribute__((ext_vector_type(4))) unsigned short ushort4x;  // 4 bf16 bits
typedef __attribute__((ext_vector_type(4))) float f32x4;              // MFMA accumulator

__device__ __forceinline__ float b2f(bf16 x) { return __bfloat162float(x); }
__device__ __forceinline__ bf16  f2b(float x) { return __float2bfloat16(x); }
__device__ __forceinline__ short bbits(float x) { bf16 b = f2b(x); short s; __builtin_memcpy(&s, &b, 2); return s; }
__device__ __forceinline__ float bu2f(unsigned short s) {
    unsigned v = ((unsigned)s) << 16; float f; __builtin_memcpy(&f, &v, 4); return f;
}
// compile-time-dispatched input load: branch-free so loads batch/pipeline.
// (runtime-flag ldin put a branch diamond around EVERY load -> serialized memory
//  pipeline; measured as the common factor in all slow duties, R0-R7)
template<int F32>
__device__ __forceinline__ float ld(const void* p, int i) {
    if constexpr (F32) return ((const float*)p)[i];
    else return b2f(((const bf16*)p)[i]);
}

// branchless erf-based gelu (A&S 7.1.26, |eps_erf| <= 1.5e-7)
__device__ __forceinline__ float gelu_f(float x) {
    const float u = x * 0.70710678118654752f;
    const float z = fabsf(u);
    const float t = __builtin_amdgcn_rcpf(fmaf(0.3275911f, z, 1.0f));
    float pl = fmaf(1.061405429f, t, -1.453152027f);
    pl = fmaf(pl, t, 1.421413741f);
    pl = fmaf(pl, t, -0.284496736f);
    pl = fmaf(pl, t, 0.254829592f);
    pl *= t;
    const float e = __builtin_amdgcn_exp2f((z * z) * -1.4426950408889634f);
    float er = fmaf(-pl, e, 1.0f);          // erf(|u|)
    er = __builtin_copysignf(er, u);        // erf(u)
    const float g = 0.5f * x;
    return fmaf(g, er, g);                  // 0.5*x*(1+erf)
}

// problem dims (fixed by setup_inputs)
#define TI 6
#define HI 40
#define WI 40
#define TO 12
#define HO 80
#define WO 80
#define NIN (TI*HI*WI)    // 9600
#define NOUT (TO*HO*WO)   // 76800

// ---------------- workspace layout ----------------
#define F_B1    0                       // [256] effective pw1 bias (o-space)
#define F_ACO   (F_B1 + 256)            // [6][256] rel-coord coefficients (o-space)
#define F_SCW   (F_ACO + 6*256)         // (unused, layout kept)
#define F_SCB   (F_SCW + 3*64)          // (unused, layout kept)
#define F_SC    (F_SCB + 4)             // [3][NIN] shortcut conv output
#define F_DT    (F_SC + 3*NIN)          // [2][TO] signed d (t axis)
#define F_DH    (F_DT + 2*TO)           // [2][HO]
#define F_DW    (F_DH + 2*HO)           // [2][WO]
#define F_FT    (F_DW + 2*WO)           // [TO] trilinear frac
#define F_FH    (F_FT + TO)             // [HO]
#define F_FW    (F_FH + HO)             // [WO]
#define F_FC2W  (F_FW + WO)             // [3*256] fc2 weights (fp32 staged)
#define F_FC2B  (F_FC2W + 768)          // [3] fc2 bias (pad 4)
#define F_B2    (F_FC2B + 4)            // [256] fc1-folded bias
#define F_A2    (F_B2 + 256)            // [6][256] fc1-folded coord coeffs
#define F_END   (F_A2 + 6*256)
#define I_IT    0
#define I_IH    (I_IT + 2*TO)
#define I_IW    (I_IH + 2*HO)
#define I_LT0   (I_IW + 2*WO)
#define I_LT1   (I_LT0 + TO)
#define I_LH0   (I_LT1 + TO)
#define I_LH1   (I_LH0 + HO)
#define I_LW0   (I_LH1 + HO)
#define I_LW1   (I_LW0 + WO)
#define I_FLAG  (I_LW1 + WO)
#define I_END   (I_FLAG + 1)

#define MPOS 32     // positions per k_main block
#define ZPAD 264    // bf16 row stride for zt LDS tiles
#define FT_S 72     // bf16 row stride for feat tile (16B-aligned rows)
#define WQS 68      // fp32 row stride for Wq GEMM LDS tiles

// dtype detection (wave-0 ballot over first 64 even halfwords of feat)
__device__ __forceinline__ int detect_f32(const void* feat, int tid, int* sh) {
    if (tid < 64) {
        const unsigned short* u = (const unsigned short*)feat;
        const unsigned e = (u[2 * tid] >> 7) & 0xFFu;
        const unsigned long long m = __ballot(e >= 0x68u && e <= 0x8Eu);
        if (tid == 0) *sh = (__popcll(m) < 32) ? 1 : 0;
    }
    __syncthreads();
    return *sh;
}

// per-axis tables, replicating reference `near` (eps=1e-6, round-half-even) and `lin_idx`
__device__ __forceinline__ void axis_tables(int i, int n_out, int n_in,
                                            float* dvals, int* ivals,
                                            int* l0, int* l1, float* fr) {
    const float r_out = 1.0f / (float)n_out;
    const float r_in  = 1.0f / (float)n_in;
    const float c = -1.0f + r_out + 2.0f * r_out * (float)i;
    #pragma unroll
    for (int v = 0; v < 2; ++v) {
        const float vv = v ? 1.0f : -1.0f;
        float cc = c + vv * r_in + 1e-6f;
        cc = fminf(fmaxf(cc, -1.0f + 1e-6f), 1.0f - 1e-6f);
        float fx = rintf(((cc + 1.0f) * (float)n_in - 1.0f) * 0.5f);
        fx = fminf(fmaxf(fx, 0.0f), (float)(n_in - 1));
        const int idx = (int)fx;
        const float l = -1.0f + r_in + 2.0f * r_in * (float)idx;
        dvals[v * n_out + i] = (c - l) * (float)n_in;
        ivals[v * n_out + i] = idx;
    }
    float x = fminf(fmaxf(((c + 1.0f) * (float)n_in - 1.0f) * 0.5f, 0.0f), (float)(n_in - 1));
    const float x0 = floorf(x);
    fr[i] = x - x0;
    const int i0 = (int)x0;
    l0[i] = i0;
    l1[i] = min(i0 + 1, n_in - 1);
}

// ---- duty: Wq fold GEMM tile (32 blocks; bit-identical order to R6/R7) ----
template<int F32>
__device__ void wq_duty(int pb, int tid, float* smem,
                        const void* dw1_w, const void* pw1_w,
                        const void* fc1_w, bf16* __restrict__ WqP) {
    const int j0 = (pb & 3) * 64;            // j tile base
    const int c0g = (pb >> 2) * 64;          // ch tile base (c' in 0..511)
    float* fcsT = smem;                      // [32 o][64 j] stride WQS
    float* pws  = smem + 32 * WQS;           // [32 o][64 ch] stride WQS
    const int tj = tid & 15, tc = tid >> 4;  // thread 4x4 register tile
    float acc[4][4] = { {0,0,0,0},{0,0,0,0},{0,0,0,0},{0,0,0,0} };

    for (int oc = 0; oc < 8; ++oc) {
        const int o0 = oc * 32;
        #pragma unroll
        for (int r = 0; r < 8; ++r) {        // fc1_w [64j x 32o] -> fcsT[o][j]
            const int idx = r * 256 + tid;
            const int o = idx & 31, jl = idx >> 5;
            fcsT[o * WQS + jl] = ld<F32>(fc1_w, (j0 + jl) * 256 + o0 + o);
        }
        #pragma unroll
        for (int r = 0; r < 8; ++r) {        // pw1_w [32o x 64ch] -> pws[o][ch]
            const int idx = r * 256 + tid;
            const int ch = idx & 63, o = idx >> 6;
            pws[o * WQS + ch] = ld<F32>(pw1_w, (o0 + o) * 539 + 24 + c0g + ch);
        }
        __syncthreads();
        #pragma unroll
        for (int o = 0; o < 32; ++o) {
            const float4 av = *(const float4*)&fcsT[o * WQS + tj * 4];
            const float4 bv = *(const float4*)&pws[o * WQS + tc * 4];
            const float a4[4] = { av.x, av.y, av.z, av.w };
            const float b4[4] = { bv.x, bv.y, bv.z, bv.w };
            #pragma unroll
            for (int ji = 0; ji < 4; ++ji)
                #pragma unroll
                for (int ci = 0; ci < 4; ++ci)
                    acc[ji][ci] = fmaf(a4[ji], b4[ci], acc[ji][ci]);
        }
        __syncthreads();
    }

    float dsc[4];
    #pragma unroll
    for (int ci = 0; ci < 4; ++ci) dsc[ci] = ld<F32>(dw1_w, 24 + c0g + tc * 4 + ci);
    const int cp0 = c0g + tc * 4;
    const int k2 = cp0 >> 5, e = (cp0 >> 3) & 3, jj0 = cp0 & 7;
    #pragma unroll
    for (int ji = 0; ji < 4; ++ji) {
        const int j = j0 + tj * 4 + ji;
        const int nt = j >> 4, wlo = j & 15;
        const size_t flat = ((((size_t)(k2 * 16 + nt) * 4 + e) * 16 + wlo) * 8 + jj0);
        short v[4];
        #pragma unroll
        for (int ci = 0; ci < 4; ++ci) v[ci] = bbits(acc[ji][ci] * dsc[ci]);
        *(short4x*)&WqP[flat] = *(short4x*)v;
    }
}

// ---- duty: B1/ACO fold for output channel o (+prep0 on o==0) ----
template<int F32>
__device__ void fold_duty(int o, int tid, float* smem,
                          const void* dw1_w, const void* dw1_b,
                          const void* pw1_w, const void* pw1_b,
                          const void* fc2_w, const void* fc2_b,
                          float* __restrict__ F, int* __restrict__ I, int f32flag) {
    float* row = smem;          // [539]
    float* red = smem + 544;    // [256]

    for (int ch = tid; ch < 539; ch += 256) row[ch] = ld<F32>(pw1_w, o * 539 + ch);
    __syncthreads();

    float s = 0.f;
    for (int ch = tid; ch < 539; ch += 256) s += row[ch] * ld<F32>(dw1_b, ch);
    red[tid] = s;
    __syncthreads();
    for (int st = 128; st > 0; st >>= 1) {
        if (tid < st) red[tid] += red[tid + st];
        __syncthreads();
    }

    if (tid == 0) {
        float bacc = ld<F32>(pw1_b, o) + red[0];
        #pragma unroll
        for (int ch = 536; ch < 539; ++ch)
            bacc += 2.0f * row[ch] * ld<F32>(dw1_w, ch);
        F[F_B1 + o] = bacc;

        float A[6] = {0.f, 0.f, 0.f, 0.f, 0.f, 0.f};
        #pragma unroll
        for (int k = 0; k < 8; ++k) {
            A[(k >> 2)]           += row[3*k + 0] * ld<F32>(dw1_w, 3*k + 0);
            A[2 + ((k >> 1) & 1)] += row[3*k + 1] * ld<F32>(dw1_w, 3*k + 1);
            A[4 + (k & 1)]        += row[3*k + 2] * ld<F32>(dw1_w, 3*k + 2);
        }
        #pragma unroll
        for (int i = 0; i < 6; ++i) F[F_ACO + i * 256 + o] = A[i];
    }

    if (o == 0) {             // ---- prep0 duty ----
        if (tid == 0) I[I_FLAG] = f32flag;
        for (int r = tid; r < 768; r += 256) F[F_FC2W + r] = ld<F32>(fc2_w, r);
        if (tid < 3) F[F_FC2B + tid] = ld<F32>(fc2_b, tid);
        if (tid < TO) axis_tables(tid, TO, TI, F + F_DT, I + I_IT, I + I_LT0, I + I_LT1, F + F_FT);
        if (tid < HO) axis_tables(tid, HO, HI, F + F_DH, I + I_IH, I + I_LH0, I + I_LH1, F + F_FH);
        if (tid < WO) axis_tables(tid, WO, WI, F + F_DW, I + I_IW, I + I_LW0, I + I_LW1, F + F_FW);
    }
}

// ---- duty: shortcut conv sc[j][pos] (113 blocks) ----
template<int F32>
__device__ void sc_duty(int b, int tid, float* smem, const void* feat,
                        const void* sc_dw_w, const void* sc_dw_b,
                        const void* sc_pw_w, const void* sc_pw_b,
                        float* __restrict__ F) {
    float* scw = smem;          // [3][64] folded weights
    float* scb = smem + 192;    // [3]
    if (tid < 192) {
        const int j = tid >> 6, c = tid & 63;
        scw[tid] = ld<F32>(sc_pw_w, j * 64 + c) * ld<F32>(sc_dw_w, c);
    }
    if (tid >= 192 && tid < 195) {
        const int j = tid - 192;
        float s = ld<F32>(sc_pw_b, j);
        for (int c = 0; c < 64; ++c)
            s += ld<F32>(sc_pw_w, j * 64 + c) * ld<F32>(sc_dw_b, c);
        scb[j] = s;
    }
    __syncthreads();
    const int g = (b - 288) * 256 + tid;
    if (g < 3 * NIN) {
        const int j = g / NIN, pos = g - j * NIN;
        float a = 0.f;
        #pragma unroll 8
        for (int c = 0; c < 64; ++c)
            a = fmaf(scw[j * 64 + c], ld<F32>(feat, c * NIN + pos), a);
        F[F_SC + g] = scb[j] + a;
    }
}

// ---------------- kernel A: merged setup (401 blocks) ----------------
// b 0..31   : Wq fold GEMM tiles (long pole -> launched first)
// b 32..287 : B1/ACO fold per o = b-32 (b==32 also prep0)
// b 288..400: shortcut conv
__global__ __launch_bounds__(256)
void k_setup(const void* __restrict__ feat,
             const void* __restrict__ dw1_w, const void* __restrict__ dw1_b,
             const void* __restrict__ pw1_w, const void* __restrict__ pw1_b,
             const void* __restrict__ fc1_w, const void* __restrict__ fc1_b,
             const void* __restrict__ fc2_w, const void* __restrict__ fc2_b,
             const void* __restrict__ sc_dw_w, const void* __restrict__ sc_dw_b,
             const void* __restrict__ sc_pw_w, const void* __restrict__ sc_pw_b,
             bf16* __restrict__ WqP, float* __restrict__ F, int* __restrict__ I) {
    const int tid = threadIdx.x;
    const int b = blockIdx.x;
    __shared__ int sflag;
    __shared__ __align__(16) float smem[2 * 32 * WQS];   // 17408 B shared by all duties
    const int f32 = detect_f32(feat, tid, &sflag);

    if (b < 32) {
        if (f32) wq_duty<1>(b, tid, smem, dw1_w, pw1_w, fc1_w, WqP);
        else     wq_duty<0>(b, tid, smem, dw1_w, pw1_w, fc1_w, WqP);
    } else if (b < 288) {
        if (f32) fold_duty<1>(b - 32, tid, smem, dw1_w, dw1_b, pw1_w, pw1_b, fc2_w, fc2_b, F, I, f32);
        else     fold_duty<0>(b - 32, tid, smem, dw1_w, dw1_b, pw1_w, pw1_b, fc2_w, fc2_b, F, I, f32);
    } else {
        if (f32) sc_duty<1>(b, tid, smem, feat, sc_dw_w, sc_dw_b, sc_pw_w, sc_pw_b, F);
        else     sc_duty<0>(b, tid, smem, feat, sc_dw_w, sc_dw_b, sc_pw_w, sc_pw_b, F);
    }
}

// ---- duty: b2/A2 fold (LDS-tiled, coalesced; o-ascending = bit-identical) ----
template<int F32>
__device__ void b2a2_fold(int tid, float* fw, float* coef,
                          const void* fc1_w, const void* fc1_b, float* __restrict__ F) {
    const int j = tid;
    float accB = ld<F32>(fc1_b, j);
    float accA[6] = {0.f,0.f,0.f,0.f,0.f,0.f};
    for (int oc = 0; oc < 8; ++oc) {
        const int o0 = oc * 32;
        __syncthreads();                     // protect fw/coef reuse
        #pragma unroll
        for (int r = 0; r < 32; ++r) {       // fc1_w [256j x 32o] -> fw[j][o], coalesced
            const int idx = r * 256 + tid;
            const int jj = idx >> 5, oo = idx & 31;
            fw[jj * 33 + oo] = ld<F32>(fc1_w, jj * 256 + o0 + oo);
        }
        if (tid < 224) {
            const int i = tid >> 5, oo = tid & 31;
            coef[tid] = F[(i == 0 ? F_B1 : F_ACO + (i - 1) * 256) + o0 + oo];
        }
        __syncthreads();
        #pragma unroll
        for (int oo = 0; oo < 32; ++oo) {
            const float f = fw[j * 33 + oo];
            accB = fmaf(f, coef[oo], accB);
            #pragma unroll
            for (int i = 0; i < 6; ++i)
                accA[i] = fmaf(f, coef[(i + 1) * 32 + oo], accA[i]);
        }
    }
    F[F_B2 + j] = accB;
    #pragma unroll
    for (int i = 0; i < 6; ++i) F[F_A2 + i * 256 + j] = accA[i];
}

// ---- k_corner main body: 2 corners together, shared A-operand ----
template<int F32>
__device__ void corner_body(int pt, int y, int tid, short* ft, short* ztA, short* ztB,
                            const void* feat, const bf16* __restrict__ WqP,
                            bf16* __restrict__ Q) {
    const int pos0 = pt * 32;
    {
        const int p = tid & 31, c0 = tid >> 5;
        #pragma unroll
        for (int cc = 0; cc < 8; ++cc) {
            const int c = c0 * 8 + cc;
            ft[p * FT_S + c] = bbits(ld<F32>(feat, c * NIN + pos0 + p));
        }
    }
    __syncthreads();

    const int wl = tid & 63, w = tid >> 6;
    const int col = wl & 15, quad = wl >> 4;
    const short8x* bp = (const short8x*)WqP;
    const int kA = y * 2, kB = y * 2 + 1;

    f32x4 accA[2][4] = { { {0,0,0,0},{0,0,0,0},{0,0,0,0},{0,0,0,0} },
                         { {0,0,0,0},{0,0,0,0},{0,0,0,0},{0,0,0,0} } };
    f32x4 accB[2][4] = { { {0,0,0,0},{0,0,0,0},{0,0,0,0},{0,0,0,0} },
                         { {0,0,0,0},{0,0,0,0},{0,0,0,0},{0,0,0,0} } };
    #pragma unroll
    for (int kc = 0; kc < 2; ++kc) {
        const short8x a0 = *(const short8x*)&ft[col * FT_S + kc * 32 + quad * 8];
        const short8x a1 = *(const short8x*)&ft[(col + 16) * FT_S + kc * 32 + quad * 8];
        #pragma unroll
        for (int nt = 0; nt < 4; ++nt) {
            const short8x bbA = bp[((kA * 2 + kc) * 16 + (w * 4 + nt)) * 64 + wl];
            const short8x bbB = bp[((kB * 2 + kc) * 16 + (w * 4 + nt)) * 64 + wl];
            accA[0][nt] = __builtin_amdgcn_mfma_f32_16x16x32_bf16(a0, bbA, accA[0][nt], 0, 0, 0);
            accA[1][nt] = __builtin_amdgcn_mfma_f32_16x16x32_bf16(a1, bbA, accA[1][nt], 0, 0, 0);
            accB[0][nt] = __builtin_amdgcn_mfma_f32_16x16x32_bf16(a0, bbB, accB[0][nt], 0, 0, 0);
            accB[1][nt] = __builtin_amdgcn_mfma_f32_16x16x32_bf16(a1, bbB, accB[1][nt], 0, 0, 0);
        }
    }

    #pragma unroll
    for (int mt = 0; mt < 2; ++mt)
        #pragma unroll
        for (int nt = 0; nt < 4; ++nt) {
            const int n = w * 64 + nt * 16 + col;
            #pragma unroll
            for (int r = 0; r < 4; ++r) {
                const int m = (mt * 16 + quad * 4 + r) * ZPAD + n;
                ztA[m] = bbits(accA[mt][nt][r]);
                ztB[m] = bbits(accB[mt][nt][r]);
            }
        }
    __syncthreads();

    #pragma unroll
    for (int q = 0; q < 4; ++q) {
        const int i = q * 256 + tid;
        const int p = i >> 5, c8 = i & 31;
        const short8x vA = *(const short8x*)&ztA[p * ZPAD + c8 * 8];
        *(short8x*)(Q + ((size_t)(kA * NIN + pos0 + p)) * 256 + c8 * 8) = vA;
    }
    #pragma unroll
    for (int q = 0; q < 4; ++q) {
        const int i = q * 256 + tid;
        const int p = i >> 5, c8 = i & 31;
        const short8x vB = *(const short8x*)&ztB[p * ZPAD + c8 * 8];
        *(short8x*)(Q + ((size_t)(kB * NIN + pos0 + p)) * 256 + c8 * 8) = vB;
    }
}

// ---------------- kernel B: MFMA corner projections Q + b2/A2 fold ----------------
__global__ __launch_bounds__(256)
void k_corner(const void* __restrict__ feat,
              const void* __restrict__ fc1_w, const void* __restrict__ fc1_b,
              float* __restrict__ F, const int* __restrict__ I,
              const bf16* __restrict__ WqP, bf16* __restrict__ Q) {
    const int tid = threadIdx.x;
    const int pt = blockIdx.x, y = blockIdx.y;
    const int f32 = I[I_FLAG];
    __shared__ __align__(16) char lds_raw[32 * FT_S * 2 + 2 * 32 * ZPAD * 2];  // 38400 B

    if (pt == 300) {          // ---- b2/A2 fold duty (one block) ----
        if (y != 0) return;
        float* fw   = (float*)lds_raw;               // [256][33] fp32 = 33792 B
        float* coef = (float*)(lds_raw + 33792);     // [7][32] = 896 B
        if (f32) b2a2_fold<1>(tid, fw, coef, fc1_w, fc1_b, F);
        else     b2a2_fold<0>(tid, fw, coef, fc1_w, fc1_b, F);
        return;
    }

    short* ft  = (short*)lds_raw;                        // 4608 B
    short* ztA = (short*)(lds_raw + 32 * FT_S * 2);      // 16896 B
    short* ztB = (short*)(lds_raw + 32 * FT_S * 2 + 32 * ZPAD * 2);
    if (f32) corner_body<1>(pt, y, tid, ft, ztA, ztB, feat, WqP, Q);
    else     corner_body<0>(pt, y, tid, ft, ztA, ztB, feat, WqP, Q);
}

// ---------------- kernel C: main fused gather->gelu->fc2 (fc1 pre-folded into Q) ----------------
__global__ __launch_bounds__(256, 4)
void k_main(const bf16* __restrict__ Q, const float* __restrict__ F,
            const int* __restrict__ I, void* __restrict__ outv) {
    const int tid = threadIdx.x;
    const int pos0 = blockIdx.x * MPOS;
    const int f32 = I[I_FLAG];

    __shared__ int   sh_ipos[MPOS][8];
    __shared__ float sh_wk[MPOS][8];
    __shared__ float sh_dv[MPOS][6];
    __shared__ float sh_g[3][MPOS];
    __shared__ float redc[4][4][8][3];   // [wave][16-lane grp][pp][jj]

    const int og = tid & 63, pg = tid >> 6;
    const int j4 = og * 4;
    const float4 b2v = *(const float4*)&F[F_B2 + j4];
    float4 A2v[6];
    #pragma unroll
    for (int i = 0; i < 6; ++i) A2v[i] = *(const float4*)&F[F_A2 + i * 256 + j4];
    const float4 fw0 = *(const float4*)&F[F_FC2W + j4];
    const float4 fw1 = *(const float4*)&F[F_FC2W + 256 + j4];
    const float4 fw2 = *(const float4*)&F[F_FC2W + 512 + j4];

    // ---- stage 1: per-position scalars (threads 0..31) ----
    if (tid < MPOS) {
        const int p = tid;
        const int pos = pos0 + p;
        const int t = pos / (HO * WO);
        const int rem = pos - t * (HO * WO);
        const int h = rem / WO;
        const int w = rem - h * WO;
        const int   iTa[2] = { I[I_IT + t], I[I_IT + TO + t] };
        const float dTv[2] = { F[F_DT + t], F[F_DT + TO + t] };
        const int   iHa[2] = { I[I_IH + h], I[I_IH + HO + h] };
        const float dHv[2] = { F[F_DH + h], F[F_DH + HO + h] };
        const int   iWa[2] = { I[I_IW + w], I[I_IW + WO + w] };
        const float dWv[2] = { F[F_DW + w], F[F_DW + WO + w] };
        sh_dv[p][0] = dTv[0]; sh_dv[p][1] = dTv[1];
        sh_dv[p][2] = dHv[0]; sh_dv[p][3] = dHv[1];
        sh_dv[p][4] = dWv[0]; sh_dv[p][5] = dWv[1];
        const float aT[2] = { fabsf(dTv[0]), fabsf(dTv[1]) };
        const float aH[2] = { fabsf(dHv[0]), fabsf(dHv[1]) };
        const float aW[2] = { fabsf(dWv[0]), fabsf(dWv[1]) };
        const float tot = (aT[0] + aT[1]) * (aH[0] + aH[1]) * (aW[0] + aW[1]) + 8e-9f;
        #pragma unroll
        for (int k = 0; k < 8; ++k) {
            const int at = k >> 2, ah = (k >> 1) & 1, aw = k & 1;
            sh_wk[p][k] = (aT[1 - at] * aH[1 - ah] * aW[1 - aw] + 1e-9f) / tot;
            sh_ipos[p][k] = iTa[at] * (HI * WI) + iHa[ah] * WI + iWa[aw];
        }
        // trilinear shortcut g
        const int a0 = I[I_LT0 + t], a1 = I[I_LT1 + t];
        const int bh0 = I[I_LH0 + h], bh1 = I[I_LH1 + h];
        const int c0 = I[I_LW0 + w], c1 = I[I_LW1 + w];
        const float fT = F[F_FT + t], fH = F[F_FH + h], fW = F[F_FW + w];
        #pragma unroll
        for (int jj = 0; jj < 3; ++jj) {
            const float* Sj = F + F_SC + jj * NIN;
            const int i0 = a0 * (HI * WI), i1 = a1 * (HI * WI);
            const float v000 = Sj[i0 + bh0 * WI + c0], v001 = Sj[i0 + bh0 * WI + c1];
            const float v010 = Sj[i0 + bh1 * WI + c0], v011 = Sj[i0 + bh1 * WI + c1];
            const float v100 = Sj[i1 + bh0 * WI + c0], v101 = Sj[i1 + bh0 * WI + c1];
            const float v110 = Sj[i1 + bh1 * WI + c0], v111 = Sj[i1 + bh1 * WI + c1];
            const float u00 = v000 * (1.f - fT) + v100 * fT;
            const float u01 = v001 * (1.f - fT) + v101 * fT;
            const float u10 = v010 * (1.f - fT) + v110 * fT;
            const float u11 = v011 * (1.f - fT) + v111 * fT;
            const float q0 = u00 * (1.f - fH) + u10 * fH;
            const float q1 = u01 * (1.f - fH) + u11 * fH;
            sh_g[jj][p] = q0 * (1.f - fW) + q1 * fW;
        }
    }
    __syncthreads();

    // ---- stage 2: gather + gelu + fc2 partials ----
    #pragma unroll
    for (int pp = 0; pp < 8; ++pp) {
        const int p = pg * 8 + pp;
        float a0 = b2v.x, a1 = b2v.y, a2 = b2v.z, a3 = b2v.w;
        #pragma unroll
        for (int i = 0; i < 6; ++i) {
            const float dv = sh_dv[p][i];
            a0 = fmaf(A2v[i].x, dv, a0); a1 = fmaf(A2v[i].y, dv, a1);
            a2 = fmaf(A2v[i].z, dv, a2); a3 = fmaf(A2v[i].w, dv, a3);
        }
        #pragma unroll
        for (int k = 0; k < 8; ++k) {
            const float wk = sh_wk[p][k];
            const ushort4x u = *(const ushort4x*)(Q + ((size_t)(k * NIN + sh_ipos[p][k])) * 256 + j4);
            a0 = fmaf(wk, bu2f(u.x), a0); a1 = fmaf(wk, bu2f(u.y), a1);
            a2 = fmaf(wk, bu2f(u.z), a2); a3 = fmaf(wk, bu2f(u.w), a3);
        }
        const float h0 = gelu_f(a0), h1 = gelu_f(a1), h2 = gelu_f(a2), h3 = gelu_f(a3);
        float pj0 = h0 * fw0.x; pj0 = fmaf(h1, fw0.y, pj0); pj0 = fmaf(h2, fw0.z, pj0); pj0 = fmaf(h3, fw0.w, pj0);
        float pj1 = h0 * fw1.x; pj1 = fmaf(h1, fw1.y, pj1); pj1 = fmaf(h2, fw1.z, pj1); pj1 = fmaf(h3, fw1.w, pj1);
        float pj2 = h0 * fw2.x; pj2 = fmaf(h1, fw2.y, pj2); pj2 = fmaf(h2, fw2.z, pj2); pj2 = fmaf(h3, fw2.w, pj2);
        #pragma unroll
        for (int m = 1; m <= 8; m <<= 1) {
            pj0 += __shfl_xor(pj0, m, 64);
            pj1 += __shfl_xor(pj1, m, 64);
            pj2 += __shfl_xor(pj2, m, 64);
        }
        if ((og & 15) == 0) {
            const int grp = og >> 4;
            redc[pg][grp][pp][0] = pj0;
            redc[pg][grp][pp][1] = pj1;
            redc[pg][grp][pp][2] = pj2;
        }
    }
    __syncthreads();

    // ---- stage 3: combine + shortcut + store ----
    if (tid < 96) {
        const int p = tid / 3, jj = tid - 3 * p;
        float a = F[F_FC2B + jj] + sh_g[jj][p];
        #pragma unroll
        for (int g4 = 0; g4 < 4; ++g4) a += redc[p >> 3][g4][p & 7][jj];
        const int oidx = jj * NOUT + pos0 + p;
        if (f32) ((float*)outv)[oidx] = a;
        else     ((bf16*)outv)[oidx] = f2b(a);
    }
}

extern "C" void kernel_launch(void* const* d_in, const int* in_sizes, int n_in,
                              void* d_out, int out_size, void* d_ws, size_t ws_size,
                              hipStream_t stream) {
    const void* feat    = d_in[0];
    const void* dw1_w   = d_in[1];
    const void* dw1_b   = d_in[2];
    const void* pw1_w   = d_in[3];
    const void* pw1_b   = d_in[4];
    const void* fc1_w   = d_in[5];
    const void* fc1_b   = d_in[6];
    const void* fc2_w   = d_in[7];
    const void* fc2_b   = d_in[8];
    const void* sc_dw_w = d_in[9];
    const void* sc_dw_b = d_in[10];
    const void* sc_pw_w = d_in[11];
    const void* sc_pw_b = d_in[12];

    const size_t Q_BYTES   = (size_t)8 * NIN * 256 * 2;   // 39,321,600
    const size_t WQP_BYTES = (size_t)16384 * 8 * 2;       // 262,144
    bf16*  Q    = (bf16*)d_ws;
    bf16*  WqP  = (bf16*)((char*)d_ws + Q_BYTES);
    float* F    = (float*)((char*)d_ws + Q_BYTES + WQP_BYTES);
    int*   I    = (int*)(F + F_END);
    // total ws need ~39.7 MB

    k_setup<<<401, 256, 0, stream>>>(feat, dw1_w, dw1_b, pw1_w, pw1_b, fc1_w, fc1_b,
                                     fc2_w, fc2_b, sc_dw_w, sc_dw_b, sc_pw_w, sc_pw_b,
                                     WqP, F, I);
    k_corner<<<dim3(301, 4), 256, 0, stream>>>(feat, fc1_w, fc1_b, F, I, WqP, Q);
    k_main<<<NOUT / MPOS, 256, 0, stream>>>(Q, F, I, (void*)d_out);
}

// Round 13
// 156.714 us; speedup vs baseline: 1.4623x; 1.0138x over previous
//
#include <hip/hip_runtime.h>
#include <hip/hip_bf16.h>

using bf16 = __hip_bfloat16;
typedef __attribute__((ext_vector_type(8))) short short8x;            // 8 bf16 (4 VGPRs)
typedef __attribute__((ext_vector_type(4))) short short4x;            // 4 bf16
typedef __attribute__((ext_vector_type(4))) unsigned short ushort4x;  // 4 bf16 bits
typedef __attribute__((ext_vector_type(4))) float f32x4;              // MFMA accumulator

__device__ __forceinline__ float b2f(bf16 x) { return __bfloat162float(x); }
__device__ __forceinline__ bf16  f2b(float x) { return __float2bfloat16(x); }
__device__ __forceinline__ short bbits(float x) { bf16 b = f2b(x); short s; __builtin_memcpy(&s, &b, 2); return s; }
__device__ __forceinline__ float bu2f(unsigned short s) {
    unsigned v = ((unsigned)s) << 16; float f; __builtin_memcpy(&f, &v, 4); return f;
}
// compile-time-dispatched input load: branch-free so loads batch/pipeline.
template<int F32>
__device__ __forceinline__ float ld(const void* p, int i) {
    if constexpr (F32) return ((const float*)p)[i];
    else return b2f(((const bf16*)p)[i]);
}

// branchless erf-based gelu (A&S 7.1.26, |eps_erf| <= 1.5e-7)
__device__ __forceinline__ float gelu_f(float x) {
    const float u = x * 0.70710678118654752f;
    const float z = fabsf(u);
    const float t = __builtin_amdgcn_rcpf(fmaf(0.3275911f, z, 1.0f));
    float pl = fmaf(1.061405429f, t, -1.453152027f);
    pl = fmaf(pl, t, 1.421413741f);
    pl = fmaf(pl, t, -0.284496736f);
    pl = fmaf(pl, t, 0.254829592f);
    pl *= t;
    const float e = __builtin_amdgcn_exp2f((z * z) * -1.4426950408889634f);
    float er = fmaf(-pl, e, 1.0f);          // erf(|u|)
    er = __builtin_copysignf(er, u);        // erf(u)
    const float g = 0.5f * x;
    return fmaf(g, er, g);                  // 0.5*x*(1+erf)
}

// problem dims (fixed by setup_inputs)
#define TI 6
#define HI 40
#define WI 40
#define TO 12
#define HO 80
#define WO 80
#define NIN (TI*HI*WI)    // 9600
#define NOUT (TO*HO*WO)   // 76800

// ---------------- workspace layout ----------------
#define F_B1    0                       // [256] effective pw1 bias (o-space)
#define F_ACO   (F_B1 + 256)            // [6][256] rel-coord coefficients (o-space)
#define F_SCW   (F_ACO + 6*256)         // (unused, layout kept)
#define F_SCB   (F_SCW + 3*64)          // (unused, layout kept)
#define F_SC    (F_SCB + 4)             // [3][NIN] shortcut conv output
#define F_DT    (F_SC + 3*NIN)          // [2][TO] signed d (t axis)
#define F_DH    (F_DT + 2*TO)           // [2][HO]
#define F_DW    (F_DH + 2*HO)           // [2][WO]
#define F_FT    (F_DW + 2*WO)           // [TO] trilinear frac
#define F_FH    (F_FT + TO)             // [HO]
#define F_FW    (F_FH + HO)             // [WO]
#define F_FC2W  (F_FW + WO)             // [3*256] fc2 weights (fp32 staged)
#define F_FC2B  (F_FC2W + 768)          // [3] fc2 bias (pad 4)
#define F_B2    (F_FC2B + 4)            // [256] fc1-folded bias
#define F_A2    (F_B2 + 256)            // [6][256] fc1-folded coord coeffs
#define F_END   (F_A2 + 6*256)
#define I_IT    0
#define I_IH    (I_IT + 2*TO)
#define I_IW    (I_IH + 2*HO)
#define I_LT0   (I_IW + 2*WO)
#define I_LT1   (I_LT0 + TO)
#define I_LH0   (I_LT1 + TO)
#define I_LH1   (I_LH0 + HO)
#define I_LW0   (I_LH1 + HO)
#define I_LW1   (I_LW0 + WO)
#define I_FLAG  (I_LW1 + WO)
#define I_END   (I_FLAG + 1)

#define MPOS 32     // positions per k_main block
#define ZPAD 264    // bf16 row stride for zt LDS tiles
#define FT_S 72     // bf16 row stride for feat tile (16B-aligned rows)
#define WQS 68      // fp32 row stride for Wq GEMM LDS tiles

// dtype detection (wave-0 ballot over first 64 even halfwords of feat)
__device__ __forceinline__ int detect_f32(const void* feat, int tid, int* sh) {
    if (tid < 64) {
        const unsigned short* u = (const unsigned short*)feat;
        const unsigned e = (u[2 * tid] >> 7) & 0xFFu;
        const unsigned long long m = __ballot(e >= 0x68u && e <= 0x8Eu);
        if (tid == 0) *sh = (__popcll(m) < 32) ? 1 : 0;
    }
    __syncthreads();
    return *sh;
}

// per-axis tables, replicating reference `near` (eps=1e-6, round-half-even) and `lin_idx`
__device__ __forceinline__ void axis_tables(int i, int n_out, int n_in,
                                            float* dvals, int* ivals,
                                            int* l0, int* l1, float* fr) {
    const float r_out = 1.0f / (float)n_out;
    const float r_in  = 1.0f / (float)n_in;
    const float c = -1.0f + r_out + 2.0f * r_out * (float)i;
    #pragma unroll
    for (int v = 0; v < 2; ++v) {
        const float vv = v ? 1.0f : -1.0f;
        float cc = c + vv * r_in + 1e-6f;
        cc = fminf(fmaxf(cc, -1.0f + 1e-6f), 1.0f - 1e-6f);
        float fx = rintf(((cc + 1.0f) * (float)n_in - 1.0f) * 0.5f);
        fx = fminf(fmaxf(fx, 0.0f), (float)(n_in - 1));
        const int idx = (int)fx;
        const float l = -1.0f + r_in + 2.0f * r_in * (float)idx;
        dvals[v * n_out + i] = (c - l) * (float)n_in;
        ivals[v * n_out + i] = idx;
    }
    float x = fminf(fmaxf(((c + 1.0f) * (float)n_in - 1.0f) * 0.5f, 0.0f), (float)(n_in - 1));
    const float x0 = floorf(x);
    fr[i] = x - x0;
    const int i0 = (int)x0;
    l0[i] = i0;
    l1[i] = min(i0 + 1, n_in - 1);
}

// ---- duty: Wq fold GEMM tile (32 blocks; bit-identical order to R6/R7) ----
template<int F32>
__device__ void wq_duty(int pb, int tid, float* smem,
                        const void* dw1_w, const void* pw1_w,
                        const void* fc1_w, bf16* __restrict__ WqP) {
    const int j0 = (pb & 3) * 64;            // j tile base
    const int c0g = (pb >> 2) * 64;          // ch tile base (c' in 0..511)
    float* fcsT = smem;                      // [32 o][64 j] stride WQS
    float* pws  = smem + 32 * WQS;           // [32 o][64 ch] stride WQS
    const int tj = tid & 15, tc = tid >> 4;  // thread 4x4 register tile
    float acc[4][4] = { {0,0,0,0},{0,0,0,0},{0,0,0,0},{0,0,0,0} };

    for (int oc = 0; oc < 8; ++oc) {
        const int o0 = oc * 32;
        #pragma unroll
        for (int r = 0; r < 8; ++r) {        // fc1_w [64j x 32o] -> fcsT[o][j]
            const int idx = r * 256 + tid;
            const int o = idx & 31, jl = idx >> 5;
            fcsT[o * WQS + jl] = ld<F32>(fc1_w, (j0 + jl) * 256 + o0 + o);
        }
        #pragma unroll
        for (int r = 0; r < 8; ++r) {        // pw1_w [32o x 64ch] -> pws[o][ch]
            const int idx = r * 256 + tid;
            const int ch = idx & 63, o = idx >> 6;
            pws[o * WQS + ch] = ld<F32>(pw1_w, (o0 + o) * 539 + 24 + c0g + ch);
        }
        __syncthreads();
        #pragma unroll
        for (int o = 0; o < 32; ++o) {
            const float4 av = *(const float4*)&fcsT[o * WQS + tj * 4];
            const float4 bv = *(const float4*)&pws[o * WQS + tc * 4];
            const float a4[4] = { av.x, av.y, av.z, av.w };
            const float b4[4] = { bv.x, bv.y, bv.z, bv.w };
            #pragma unroll
            for (int ji = 0; ji < 4; ++ji)
                #pragma unroll
                for (int ci = 0; ci < 4; ++ci)
                    acc[ji][ci] = fmaf(a4[ji], b4[ci], acc[ji][ci]);
        }
        __syncthreads();
    }

    float dsc[4];
    #pragma unroll
    for (int ci = 0; ci < 4; ++ci) dsc[ci] = ld<F32>(dw1_w, 24 + c0g + tc * 4 + ci);
    const int cp0 = c0g + tc * 4;
    const int k2 = cp0 >> 5, e = (cp0 >> 3) & 3, jj0 = cp0 & 7;
    #pragma unroll
    for (int ji = 0; ji < 4; ++ji) {
        const int j = j0 + tj * 4 + ji;
        const int nt = j >> 4, wlo = j & 15;
        const size_t flat = ((((size_t)(k2 * 16 + nt) * 4 + e) * 16 + wlo) * 8 + jj0);
        short v[4];
        #pragma unroll
        for (int ci = 0; ci < 4; ++ci) v[ci] = bbits(acc[ji][ci] * dsc[ci]);
        *(short4x*)&WqP[flat] = *(short4x*)v;
    }
}

// ---- duty: B1/ACO fold for output channel o (+prep0 on o==0) ----
template<int F32>
__device__ void fold_duty(int o, int tid, float* smem,
                          const void* dw1_w, const void* dw1_b,
                          const void* pw1_w, const void* pw1_b,
                          const void* fc2_w, const void* fc2_b,
                          float* __restrict__ F, int* __restrict__ I, int f32flag) {
    float* row = smem;          // [539]
    float* red = smem + 544;    // [256]

    for (int ch = tid; ch < 539; ch += 256) row[ch] = ld<F32>(pw1_w, o * 539 + ch);
    __syncthreads();

    float s = 0.f;
    for (int ch = tid; ch < 539; ch += 256) s += row[ch] * ld<F32>(dw1_b, ch);
    red[tid] = s;
    __syncthreads();
    for (int st = 128; st > 0; st >>= 1) {
        if (tid < st) red[tid] += red[tid + st];
        __syncthreads();
    }

    if (tid == 0) {
        float bacc = ld<F32>(pw1_b, o) + red[0];
        #pragma unroll
        for (int ch = 536; ch < 539; ++ch)
            bacc += 2.0f * row[ch] * ld<F32>(dw1_w, ch);
        F[F_B1 + o] = bacc;

        float A[6] = {0.f, 0.f, 0.f, 0.f, 0.f, 0.f};
        #pragma unroll
        for (int k = 0; k < 8; ++k) {
            A[(k >> 2)]           += row[3*k + 0] * ld<F32>(dw1_w, 3*k + 0);
            A[2 + ((k >> 1) & 1)] += row[3*k + 1] * ld<F32>(dw1_w, 3*k + 1);
            A[4 + (k & 1)]        += row[3*k + 2] * ld<F32>(dw1_w, 3*k + 2);
        }
        #pragma unroll
        for (int i = 0; i < 6; ++i) F[F_ACO + i * 256 + o] = A[i];
    }

    if (o == 0) {             // ---- prep0 duty ----
        if (tid == 0) I[I_FLAG] = f32flag;
        for (int r = tid; r < 768; r += 256) F[F_FC2W + r] = ld<F32>(fc2_w, r);
        if (tid < 3) F[F_FC2B + tid] = ld<F32>(fc2_b, tid);
        if (tid < TO) axis_tables(tid, TO, TI, F + F_DT, I + I_IT, I + I_LT0, I + I_LT1, F + F_FT);
        if (tid < HO) axis_tables(tid, HO, HI, F + F_DH, I + I_IH, I + I_LH0, I + I_LH1, F + F_FH);
        if (tid < WO) axis_tables(tid, WO, WI, F + F_DW, I + I_IW, I + I_LW0, I + I_LW1, F + F_FW);
    }
}

// ---- duty: shortcut conv sc[j][pos] (113 blocks) ----
template<int F32>
__device__ void sc_duty(int b, int tid, float* smem, const void* feat,
                        const void* sc_dw_w, const void* sc_dw_b,
                        const void* sc_pw_w, const void* sc_pw_b,
                        float* __restrict__ F) {
    float* scw = smem;          // [3][64] folded weights
    float* scb = smem + 192;    // [3]
    if (tid < 192) {
        const int j = tid >> 6, c = tid & 63;
        scw[tid] = ld<F32>(sc_pw_w, j * 64 + c) * ld<F32>(sc_dw_w, c);
    }
    if (tid >= 192 && tid < 195) {
        const int j = tid - 192;
        float s = ld<F32>(sc_pw_b, j);
        for (int c = 0; c < 64; ++c)
            s += ld<F32>(sc_pw_w, j * 64 + c) * ld<F32>(sc_dw_b, c);
        scb[j] = s;
    }
    __syncthreads();
    const int g = (b - 288) * 256 + tid;
    if (g < 3 * NIN) {
        const int j = g / NIN, pos = g - j * NIN;
        float a = 0.f;
        #pragma unroll 8
        for (int c = 0; c < 64; ++c)
            a = fmaf(scw[j * 64 + c], ld<F32>(feat, c * NIN + pos), a);
        F[F_SC + g] = scb[j] + a;
    }
}

// ---------------- kernel A: merged setup (401 blocks) ----------------
__global__ __launch_bounds__(256)
void k_setup(const void* __restrict__ feat,
             const void* __restrict__ dw1_w, const void* __restrict__ dw1_b,
             const void* __restrict__ pw1_w, const void* __restrict__ pw1_b,
             const void* __restrict__ fc1_w, const void* __restrict__ fc1_b,
             const void* __restrict__ fc2_w, const void* __restrict__ fc2_b,
             const void* __restrict__ sc_dw_w, const void* __restrict__ sc_dw_b,
             const void* __restrict__ sc_pw_w, const void* __restrict__ sc_pw_b,
             bf16* __restrict__ WqP, float* __restrict__ F, int* __restrict__ I) {
    const int tid = threadIdx.x;
    const int b = blockIdx.x;
    __shared__ int sflag;
    __shared__ __align__(16) float smem[2 * 32 * WQS];   // 17408 B shared by all duties
    const int f32 = detect_f32(feat, tid, &sflag);

    if (b < 32) {
        if (f32) wq_duty<1>(b, tid, smem, dw1_w, pw1_w, fc1_w, WqP);
        else     wq_duty<0>(b, tid, smem, dw1_w, pw1_w, fc1_w, WqP);
    } else if (b < 288) {
        if (f32) fold_duty<1>(b - 32, tid, smem, dw1_w, dw1_b, pw1_w, pw1_b, fc2_w, fc2_b, F, I, f32);
        else     fold_duty<0>(b - 32, tid, smem, dw1_w, dw1_b, pw1_w, pw1_b, fc2_w, fc2_b, F, I, f32);
    } else {
        if (f32) sc_duty<1>(b, tid, smem, feat, sc_dw_w, sc_dw_b, sc_pw_w, sc_pw_b, F);
        else     sc_duty<0>(b, tid, smem, feat, sc_dw_w, sc_dw_b, sc_pw_w, sc_pw_b, F);
    }
}

// ---- duty: b2/A2 fold (LDS-tiled, coalesced; o-ascending = bit-identical) ----
template<int F32>
__device__ void b2a2_fold(int tid, float* fw, float* coef,
                          const void* fc1_w, const void* fc1_b, float* __restrict__ F) {
    const int j = tid;
    float accB = ld<F32>(fc1_b, j);
    float accA[6] = {0.f,0.f,0.f,0.f,0.f,0.f};
    for (int oc = 0; oc < 8; ++oc) {
        const int o0 = oc * 32;
        __syncthreads();                     // protect fw/coef reuse
        #pragma unroll
        for (int r = 0; r < 32; ++r) {       // fc1_w [256j x 32o] -> fw[j][o], coalesced
            const int idx = r * 256 + tid;
            const int jj = idx >> 5, oo = idx & 31;
            fw[jj * 33 + oo] = ld<F32>(fc1_w, jj * 256 + o0 + oo);
        }
        if (tid < 224) {
            const int i = tid >> 5, oo = tid & 31;
            coef[tid] = F[(i == 0 ? F_B1 : F_ACO + (i - 1) * 256) + o0 + oo];
        }
        __syncthreads();
        #pragma unroll
        for (int oo = 0; oo < 32; ++oo) {
            const float f = fw[j * 33 + oo];
            accB = fmaf(f, coef[oo], accB);
            #pragma unroll
            for (int i = 0; i < 6; ++i)
                accA[i] = fmaf(f, coef[(i + 1) * 32 + oo], accA[i]);
        }
    }
    F[F_B2 + j] = accB;
    #pragma unroll
    for (int i = 0; i < 6; ++i) F[F_A2 + i * 256 + j] = accA[i];
}

// ---- k_corner main body: 2 corners together, shared A-operand ----
template<int F32>
__device__ void corner_body(int pt, int y, int tid, short* ft, short* ztA, short* ztB,
                            const void* feat, const bf16* __restrict__ WqP,
                            bf16* __restrict__ Q) {
    const int pos0 = pt * 32;
    {
        const int p = tid & 31, c0 = tid >> 5;
        #pragma unroll
        for (int cc = 0; cc < 8; ++cc) {
            const int c = c0 * 8 + cc;
            ft[p * FT_S + c] = bbits(ld<F32>(feat, c * NIN + pos0 + p));
        }
    }
    __syncthreads();

    const int wl = tid & 63, w = tid >> 6;
    const int col = wl & 15, quad = wl >> 4;
    const short8x* bp = (const short8x*)WqP;
    const int kA = y * 2, kB = y * 2 + 1;

    f32x4 accA[2][4] = { { {0,0,0,0},{0,0,0,0},{0,0,0,0},{0,0,0,0} },
                         { {0,0,0,0},{0,0,0,0},{0,0,0,0},{0,0,0,0} } };
    f32x4 accB[2][4] = { { {0,0,0,0},{0,0,0,0},{0,0,0,0},{0,0,0,0} },
                         { {0,0,0,0},{0,0,0,0},{0,0,0,0},{0,0,0,0} } };
    #pragma unroll
    for (int kc = 0; kc < 2; ++kc) {
        const short8x a0 = *(const short8x*)&ft[col * FT_S + kc * 32 + quad * 8];
        const short8x a1 = *(const short8x*)&ft[(col + 16) * FT_S + kc * 32 + quad * 8];
        #pragma unroll
        for (int nt = 0; nt < 4; ++nt) {
            const short8x bbA = bp[((kA * 2 + kc) * 16 + (w * 4 + nt)) * 64 + wl];
            const short8x bbB = bp[((kB * 2 + kc) * 16 + (w * 4 + nt)) * 64 + wl];
            accA[0][nt] = __builtin_amdgcn_mfma_f32_16x16x32_bf16(a0, bbA, accA[0][nt], 0, 0, 0);
            accA[1][nt] = __builtin_amdgcn_mfma_f32_16x16x32_bf16(a1, bbA, accA[1][nt], 0, 0, 0);
            accB[0][nt] = __builtin_amdgcn_mfma_f32_16x16x32_bf16(a0, bbB, accB[0][nt], 0, 0, 0);
            accB[1][nt] = __builtin_amdgcn_mfma_f32_16x16x32_bf16(a1, bbB, accB[1][nt], 0, 0, 0);
        }
    }

    #pragma unroll
    for (int mt = 0; mt < 2; ++mt)
        #pragma unroll
        for (int nt = 0; nt < 4; ++nt) {
            const int n = w * 64 + nt * 16 + col;
            #pragma unroll
            for (int r = 0; r < 4; ++r) {
                const int m = (mt * 16 + quad * 4 + r) * ZPAD + n;
                ztA[m] = bbits(accA[mt][nt][r]);
                ztB[m] = bbits(accB[mt][nt][r]);
            }
        }
    __syncthreads();

    #pragma unroll
    for (int q = 0; q < 4; ++q) {
        const int i = q * 256 + tid;
        const int p = i >> 5, c8 = i & 31;
        const short8x vA = *(const short8x*)&ztA[p * ZPAD + c8 * 8];
        *(short8x*)(Q + ((size_t)(kA * NIN + pos0 + p)) * 256 + c8 * 8) = vA;
    }
    #pragma unroll
    for (int q = 0; q < 4; ++q) {
        const int i = q * 256 + tid;
        const int p = i >> 5, c8 = i & 31;
        const short8x vB = *(const short8x*)&ztB[p * ZPAD + c8 * 8];
        *(short8x*)(Q + ((size_t)(kB * NIN + pos0 + p)) * 256 + c8 * 8) = vB;
    }
}

// ---------------- kernel B: MFMA corner projections Q + b2/A2 fold ----------------
__global__ __launch_bounds__(256)
void k_corner(const void* __restrict__ feat,
              const void* __restrict__ fc1_w, const void* __restrict__ fc1_b,
              float* __restrict__ F, const int* __restrict__ I,
              const bf16* __restrict__ WqP, bf16* __restrict__ Q) {
    const int tid = threadIdx.x;
    const int pt = blockIdx.x, y = blockIdx.y;
    const int f32 = I[I_FLAG];
    __shared__ __align__(16) char lds_raw[32 * FT_S * 2 + 2 * 32 * ZPAD * 2];  // 38400 B

    if (pt == 300) {          // ---- b2/A2 fold duty (one block) ----
        if (y != 0) return;
        float* fw   = (float*)lds_raw;               // [256][33] fp32 = 33792 B
        float* coef = (float*)(lds_raw + 33792);     // [7][32] = 896 B
        if (f32) b2a2_fold<1>(tid, fw, coef, fc1_w, fc1_b, F);
        else     b2a2_fold<0>(tid, fw, coef, fc1_w, fc1_b, F);
        return;
    }

    short* ft  = (short*)lds_raw;                        // 4608 B
    short* ztA = (short*)(lds_raw + 32 * FT_S * 2);      // 16896 B
    short* ztB = (short*)(lds_raw + 32 * FT_S * 2 + 32 * ZPAD * 2);
    if (f32) corner_body<1>(pt, y, tid, ft, ztA, ztB, feat, WqP, Q);
    else     corner_body<0>(pt, y, tid, ft, ztA, ztB, feat, WqP, Q);
}

// per-position compute for k_main stage 2 (u = 8 prefetched corner fragments)
#define KM_COMPUTE(PP, U)                                                              \
    do {                                                                               \
        const int p_ = pg * 8 + (PP);                                                  \
        float a0 = b2v.x, a1 = b2v.y, a2 = b2v.z, a3 = b2v.w;                          \
        _Pragma("unroll")                                                              \
        for (int i = 0; i < 6; ++i) {                                                  \
            const float dv = sh_dv[p_][i];                                             \
            a0 = fmaf(A2v[i].x, dv, a0); a1 = fmaf(A2v[i].y, dv, a1);                  \
            a2 = fmaf(A2v[i].z, dv, a2); a3 = fmaf(A2v[i].w, dv, a3);                  \
        }                                                                              \
        _Pragma("unroll")                                                              \
        for (int k = 0; k < 8; ++k) {                                                  \
            const float wk = sh_wk[p_][k];                                             \
            a0 = fmaf(wk, bu2f(U[k].x), a0); a1 = fmaf(wk, bu2f(U[k].y), a1);          \
            a2 = fmaf(wk, bu2f(U[k].z), a2); a3 = fmaf(wk, bu2f(U[k].w), a3);          \
        }                                                                              \
        const float h0 = gelu_f(a0), h1 = gelu_f(a1), h2 = gelu_f(a2), h3 = gelu_f(a3);\
        float pj0 = h0 * fw0.x; pj0 = fmaf(h1, fw0.y, pj0);                            \
        pj0 = fmaf(h2, fw0.z, pj0); pj0 = fmaf(h3, fw0.w, pj0);                        \
        float pj1 = h0 * fw1.x; pj1 = fmaf(h1, fw1.y, pj1);                            \
        pj1 = fmaf(h2, fw1.z, pj1); pj1 = fmaf(h3, fw1.w, pj1);                        \
        float pj2 = h0 * fw2.x; pj2 = fmaf(h1, fw2.y, pj2);                            \
        pj2 = fmaf(h2, fw2.z, pj2); pj2 = fmaf(h3, fw2.w, pj2);                        \
        _Pragma("unroll")                                                              \
        for (int m = 1; m <= 8; m <<= 1) {                                             \
            pj0 += __shfl_xor(pj0, m, 64);                                             \
            pj1 += __shfl_xor(pj1, m, 64);                                             \
            pj2 += __shfl_xor(pj2, m, 64);                                             \
        }                                                                              \
        if ((og & 15) == 0) {                                                          \
            const int grp = og >> 4;                                                   \
            redc[pg][grp][(PP)][0] = pj0;                                              \
            redc[pg][grp][(PP)][1] = pj1;                                              \
            redc[pg][grp][(PP)][2] = pj2;                                              \
        }                                                                              \
    } while (0)

// ---------------- kernel C: main fused gather->gelu->fc2 (fc1 pre-folded into Q) ----------------
__global__ __launch_bounds__(256, 4)
void k_main(const bf16* __restrict__ Q, const float* __restrict__ F,
            const int* __restrict__ I, void* __restrict__ outv) {
    const int tid = threadIdx.x;
    const int pos0 = blockIdx.x * MPOS;
    const int f32 = I[I_FLAG];

    __shared__ int   sh_ipos[MPOS][8];   // pre-multiplied: (k*NIN + ipos) * 256
    __shared__ float sh_wk[MPOS][8];
    __shared__ float sh_dv[MPOS][6];
    __shared__ float sh_g[3][MPOS];
    __shared__ float redc[4][4][8][3];   // [wave][16-lane grp][pp][jj]

    const int og = tid & 63, pg = tid >> 6;
    const int j4 = og * 4;
    const float4 b2v = *(const float4*)&F[F_B2 + j4];
    float4 A2v[6];
    #pragma unroll
    for (int i = 0; i < 6; ++i) A2v[i] = *(const float4*)&F[F_A2 + i * 256 + j4];
    const float4 fw0 = *(const float4*)&F[F_FC2W + j4];
    const float4 fw1 = *(const float4*)&F[F_FC2W + 256 + j4];
    const float4 fw2 = *(const float4*)&F[F_FC2W + 512 + j4];

    // ---- stage 1a: per-position gather scalars (threads 0..31) ----
    if (tid < MPOS) {
        const int p = tid;
        const int pos = pos0 + p;
        const int t = pos / (HO * WO);
        const int rem = pos - t * (HO * WO);
        const int h = rem / WO;
        const int w = rem - h * WO;
        const int   iTa[2] = { I[I_IT + t], I[I_IT + TO + t] };
        const float dTv[2] = { F[F_DT + t], F[F_DT + TO + t] };
        const int   iHa[2] = { I[I_IH + h], I[I_IH + HO + h] };
        const float dHv[2] = { F[F_DH + h], F[F_DH + HO + h] };
        const int   iWa[2] = { I[I_IW + w], I[I_IW + WO + w] };
        const float dWv[2] = { F[F_DW + w], F[F_DW + WO + w] };
        sh_dv[p][0] = dTv[0]; sh_dv[p][1] = dTv[1];
        sh_dv[p][2] = dHv[0]; sh_dv[p][3] = dHv[1];
        sh_dv[p][4] = dWv[0]; sh_dv[p][5] = dWv[1];
        const float aT[2] = { fabsf(dTv[0]), fabsf(dTv[1]) };
        const float aH[2] = { fabsf(dHv[0]), fabsf(dHv[1]) };
        const float aW[2] = { fabsf(dWv[0]), fabsf(dWv[1]) };
        const float tot = (aT[0] + aT[1]) * (aH[0] + aH[1]) * (aW[0] + aW[1]) + 8e-9f;
        #pragma unroll
        for (int k = 0; k < 8; ++k) {
            const int at = k >> 2, ah = (k >> 1) & 1, aw = k & 1;
            sh_wk[p][k] = (aT[1 - at] * aH[1 - ah] * aW[1 - aw] + 1e-9f) / tot;
            sh_ipos[p][k] = (iTa[at] * (HI * WI) + iHa[ah] * WI + iWa[aw] + k * NIN) * 256;
        }
    }
    // ---- stage 1b: trilinear shortcut g (threads 32..127, one (jj,p) each) ----
    if (tid >= 32 && tid < 128) {
        const int p = tid & 31, jj = (tid >> 5) - 1;
        const int pos = pos0 + p;
        const int t = pos / (HO * WO);
        const int rem = pos - t * (HO * WO);
        const int h = rem / WO;
        const int w = rem - h * WO;
        const int a0i = I[I_LT0 + t], a1i = I[I_LT1 + t];
        const int bh0 = I[I_LH0 + h], bh1 = I[I_LH1 + h];
        const int c0 = I[I_LW0 + w], c1 = I[I_LW1 + w];
        const float fT = F[F_FT + t], fH = F[F_FH + h], fW = F[F_FW + w];
        const float* Sj = F + F_SC + jj * NIN;
        const int i0 = a0i * (HI * WI), i1 = a1i * (HI * WI);
        const float v000 = Sj[i0 + bh0 * WI + c0], v001 = Sj[i0 + bh0 * WI + c1];
        const float v010 = Sj[i0 + bh1 * WI + c0], v011 = Sj[i0 + bh1 * WI + c1];
        const float v100 = Sj[i1 + bh0 * WI + c0], v101 = Sj[i1 + bh0 * WI + c1];
        const float v110 = Sj[i1 + bh1 * WI + c0], v111 = Sj[i1 + bh1 * WI + c1];
        const float u00 = v000 * (1.f - fT) + v100 * fT;
        const float u01 = v001 * (1.f - fT) + v101 * fT;
        const float u10 = v010 * (1.f - fT) + v110 * fT;
        const float u11 = v011 * (1.f - fT) + v111 * fT;
        const float q0 = u00 * (1.f - fH) + u10 * fH;
        const float q1 = u01 * (1.f - fH) + u11 * fH;
        sh_g[jj][p] = q0 * (1.f - fW) + q1 * fW;
    }
    __syncthreads();

    // ---- stage 2: gather + gelu + fc2 partials, 2-deep A/B load pipeline ----
    const bf16* Qb = Q;
    ushort4x uA[8], uB[8];
    #pragma unroll
    for (int k = 0; k < 8; ++k)
        uA[k] = *(const ushort4x*)(Qb + (size_t)(unsigned)sh_ipos[pg * 8 + 0][k] + j4);
    #pragma unroll
    for (int pp2 = 0; pp2 < 8; pp2 += 2) {
        #pragma unroll
        for (int k = 0; k < 8; ++k)
            uB[k] = *(const ushort4x*)(Qb + (size_t)(unsigned)sh_ipos[pg * 8 + pp2 + 1][k] + j4);
        KM_COMPUTE(pp2, uA);
        if (pp2 + 2 < 8) {
            #pragma unroll
            for (int k = 0; k < 8; ++k)
                uA[k] = *(const ushort4x*)(Qb + (size_t)(unsigned)sh_ipos[pg * 8 + pp2 + 2][k] + j4);
        }
        KM_COMPUTE(pp2 + 1, uB);
    }
    __syncthreads();

    // ---- stage 3: combine + shortcut + store ----
    if (tid < 96) {
        const int p = tid / 3, jj = tid - 3 * p;
        float a = F[F_FC2B + jj] + sh_g[jj][p];
        #pragma unroll
        for (int g4 = 0; g4 < 4; ++g4) a += redc[p >> 3][g4][p & 7][jj];
        const int oidx = jj * NOUT + pos0 + p;
        if (f32) ((float*)outv)[oidx] = a;
        else     ((bf16*)outv)[oidx] = f2b(a);
    }
}

extern "C" void kernel_launch(void* const* d_in, const int* in_sizes, int n_in,
                              void* d_out, int out_size, void* d_ws, size_t ws_size,
                              hipStream_t stream) {
    const void* feat    = d_in[0];
    const void* dw1_w   = d_in[1];
    const void* dw1_b   = d_in[2];
    const void* pw1_w   = d_in[3];
    const void* pw1_b   = d_in[4];
    const void* fc1_w   = d_in[5];
    const void* fc1_b   = d_in[6];
    const void* fc2_w   = d_in[7];
    const void* fc2_b   = d_in[8];
    const void* sc_dw_w = d_in[9];
    const void* sc_dw_b = d_in[10];
    const void* sc_pw_w = d_in[11];
    const void* sc_pw_b = d_in[12];

    const size_t Q_BYTES   = (size_t)8 * NIN * 256 * 2;   // 39,321,600
    const size_t WQP_BYTES = (size_t)16384 * 8 * 2;       // 262,144
    bf16*  Q    = (bf16*)d_ws;
    bf16*  WqP  = (bf16*)((char*)d_ws + Q_BYTES);
    float* F    = (float*)((char*)d_ws + Q_BYTES + WQP_BYTES);
    int*   I    = (int*)(F + F_END);
    // total ws need ~39.7 MB

    k_setup<<<401, 256, 0, stream>>>(feat, dw1_w, dw1_b, pw1_w, pw1_b, fc1_w, fc1_b,
                                     fc2_w, fc2_b, sc_dw_w, sc_dw_b, sc_pw_w, sc_pw_b,
                                     WqP, F, I);
    k_corner<<<dim3(301, 4), 256, 0, stream>>>(feat, fc1_w, fc1_b, F, I, WqP, Q);
    k_main<<<NOUT / MPOS, 256, 0, stream>>>(Q, F, I, (void*)d_out);
}